// Round 1
// baseline (129.293 us; speedup 1.0000x reference)
//
#include <hip/hip_runtime.h>
#include <stdint.h>

#define IMW 512
#define HW 262144  // 512*512

typedef unsigned long long ull;

// ---------------------------------------------------------------------------
// k0: rearrange clip conv weights for scalar-friendly access.
// w2r[(j*4 + ic/4)*128 + oc*4 + ic%4] = clip_w2[oc][ic][j]   (j = dy*3+dx)
// w1r[tap*16 + oc] = clip_w1[oc][tap]                        (tap = ic*9+j)
// ---------------------------------------------------------------------------
__global__ __launch_bounds__(256) void k0_rearrange(
    const float* __restrict__ cw2, const float* __restrict__ cw1,
    float* __restrict__ w2r, float* __restrict__ w1r) {
  int i = blockIdx.x * 256 + threadIdx.x;
  if (i < 4608) {
    int oc = i / 144, rem = i % 144;
    int ic = rem / 9, j = rem % 9;
    w2r[(j * 4 + (ic >> 2)) * 128 + oc * 4 + (ic & 3)] = cw2[i];
  }
  if (i < 720) {
    int oc = i / 45, tap = i % 45;
    w1r[tap * 16 + oc] = cw1[i];
  }
}

// ---------------------------------------------------------------------------
// k1: LIF scan over 64 frames (bit-exact fp32: v = v + (x-v)/10, spike v>=1,
// hard reset). Transposes spikes via __ballot into row bitmaps:
// R[enc][t][y][wc] = 64-bit word, bit i = spike at column wc*64+i.
// ---------------------------------------------------------------------------
__global__ __launch_bounds__(256) void k1_lif(
    const float* __restrict__ on, const float* __restrict__ off,
    ull* __restrict__ R) {
  const float* ev = blockIdx.z ? off : on;
  int y = blockIdx.y;
  int x = blockIdx.x * 256 + threadIdx.x;
  int lane = threadIdx.x & 63;
  const float* p = ev + y * IMW + x;
  float v = 0.0f;
  ull keep = 0;
#pragma unroll
  for (int t = 0; t < 64; ++t) {
    float xv = p[(size_t)t * HW];
    v = v + (xv - v) / 10.0f;   // IEEE div, matches reference exactly
    int s = (v >= 1.0f) ? 1 : 0;
    if (s) v = 0.0f;
    ull bal = __ballot(s);
    if (lane == t) keep = bal;
  }
  int wc = blockIdx.x * 4 + (threadIdx.x >> 6);
  R[(((size_t)blockIdx.z * 64 + lane) * IMW + y) * 8 + wc] = keep;
}

// ---------------------------------------------------------------------------
// k2: encoder convs. Tile 64x4 output pixels, 1 px/thread (4 waves = 4 rows).
// Fast path: if no spike anywhere in the tile's 5x5 halo across all 64 t,
// output is exactly 0 (relu(conv2(relu(conv1(0)))) with no biases).
// Slow path: relu(conv1) via 512-entry float4 table indexed by 3x3 spike
// pattern, conv2 in registers, conv2 zero-padding handled by fm[] masks.
// ---------------------------------------------------------------------------
__global__ __launch_bounds__(256) void k2_enc(
    const ull* __restrict__ R, const float* __restrict__ on_w1,
    const float* __restrict__ on_w2, const float* __restrict__ off_w1,
    const float* __restrict__ off_w2, float* __restrict__ means) {
  __shared__ ull spk[64][8][2];   // [t][local row r0-2..r0+5][A,B]
  __shared__ float4 t1v[512];     // relu(conv1) per 9-bit pattern
  int tid = threadIdx.x;
  int enc = blockIdx.z;
  int wcb = blockIdx.x;           // 64-column word index 0..7
  int r0 = blockIdx.y * 4;
  ull any = 0;
#pragma unroll
  for (int i = 0; i < 2; ++i) {
    int pair = tid * 2 + i;       // 512 pairs = 64 t x 8 rows
    int t = pair >> 3, row = pair & 7;
    int gy = r0 - 2 + row;
    ull Wp = 0, Wc = 0, Wn = 0;
    if (gy >= 0 && gy < IMW) {
      const ull* base = R + (((size_t)enc * 64 + t) * IMW + gy) * 8;
      Wc = base[wcb];
      if (wcb > 0) Wp = base[wcb - 1];
      if (wcb < 7) Wn = base[wcb + 1];
    }
    spk[t][row][0] = (Wc << 2) | (Wp >> 62);  // A: cols C-2..C+61
    spk[t][row][1] = (Wc >> 2) | (Wn << 62);  // B: cols C+2..C+65
    any |= Wp | Wc | Wn;
  }
  int lane = tid & 63, wv = tid >> 6;
  int c = wcb * 64 + lane;
  int r = r0 + wv;
  float* outp = means + (size_t)enc * HW + r * IMW + c;
  int nz = __syncthreads_or(any != 0ull);
  if (!nz) { *outp = 0.0f; return; }

  // ---- slow path (not executed for all-zero spikes, but fully correct) ----
  const float* w1 = enc ? off_w1 : on_w1;
  const float* w2 = enc ? off_w2 : on_w2;
#pragma unroll
  for (int i = 0; i < 2; ++i) {
    int e = tid + 256 * i;
    float a0 = 0.f, a1 = 0.f, a2 = 0.f, a3 = 0.f;
#pragma unroll
    for (int k = 0; k < 9; ++k) {
      if (e & (1 << k)) {
        a0 += w1[k]; a1 += w1[9 + k]; a2 += w1[18 + k]; a3 += w1[27 + k];
      }
    }
    t1v[e] = make_float4(fmaxf(a0, 0.f), fmaxf(a1, 0.f),
                         fmaxf(a2, 0.f), fmaxf(a3, 0.f));
  }
  __syncthreads();
  float w2g[36];
#pragma unroll
  for (int i = 0; i < 36; ++i) w2g[i] = w2[i];
  float fm[9];   // conv2 zero-padding: out-of-image positions contribute 0
#pragma unroll
  for (int qi = 0; qi < 3; ++qi)
#pragma unroll
    for (int dx = 0; dx < 3; ++dx) {
      int q = r - 1 + qi, xp = c - 1 + dx;
      fm[qi * 3 + dx] =
          (q >= 0 && q < IMW && xp >= 0 && xp < IMW) ? 1.0f : 0.0f;
    }
  int selB = (lane >= 60) ? 1 : 0;
  int shamt = selB ? lane - 4 : lane;
  float acc = 0.0f;
  for (int t = 0; t < 64; ++t) {
    unsigned r5[5];
#pragma unroll
    for (int k = 0; k < 5; ++k)
      r5[k] = (unsigned)((spk[t][wv + k][selB] >> shamt) & 31ull);
    float sum = 0.0f;
#pragma unroll
    for (int qi = 0; qi < 3; ++qi) {
#pragma unroll
      for (int dx = 0; dx < 3; ++dx) {
        unsigned pat = ((r5[qi] >> dx) & 7u) |
                       (((r5[qi + 1] >> dx) & 7u) << 3) |
                       (((r5[qi + 2] >> dx) & 7u) << 6);
        float4 sv = t1v[pat];
        int j = qi * 3 + dx;
        float d = w2g[j] * sv.x + w2g[9 + j] * sv.y + w2g[18 + j] * sv.z +
                  w2g[27 + j] * sv.w;
        sum = fmaf(fm[j], d, sum);
      }
    }
    acc += fmaxf(sum, 0.0f);
  }
  *outp = acc * (1.0f / 64.0f);
}

// ---------------------------------------------------------------------------
// k3: clip convs, fused. Out tile 32x16. Phase1 builds relu(conv1+b1) for
// tile+halo (zeroed at out-of-image positions = conv2 zero padding) into LDS.
// Phase2: register tile 8 oc x 8 px per thread, weights via uniform (scalar)
// loads, stage via ds_read_b128.
// ---------------------------------------------------------------------------
__global__ __launch_bounds__(256) void k3_clip(
    const float* __restrict__ means, const float* __restrict__ rgb,
    const float* __restrict__ w1r, const float* __restrict__ b1,
    const float* __restrict__ w2r, const float* __restrict__ b2,
    float* __restrict__ out) {
  __shared__ float xs[5][20][36];       // input tile, rows r0-2.., cols c0-2..
  __shared__ float stage[18 * 34 * 20]; // [sr][sc][16 ic, padded to 20]
  int tid = threadIdx.x;
  int c0 = blockIdx.x * 32;
  int r0 = blockIdx.y * 16;
  // load x tile (On mean, Off mean, rgb x3) with zero padding
#pragma unroll
  for (int k = 0; k < 15; ++k) {
    int idx = tid + 256 * k;
    if (idx < 3600) {
      int ch = idx / 720, rem = idx % 720;
      int row = rem / 36, col = rem % 36;
      int gy = r0 - 2 + row, gx = c0 - 2 + col;
      float val = 0.0f;
      if (gy >= 0 && gy < IMW && gx >= 0 && gx < IMW) {
        val = (ch < 2) ? means[(size_t)ch * HW + gy * IMW + gx]
                       : rgb[(size_t)(ch - 2) * HW + gy * IMW + gx];
      }
      xs[ch][row][col] = val;
    }
  }
  __syncthreads();
  // ---- phase 1: stage = relu(conv1(x)+b1), 612 positions, <=3 per thread
  {
    int p0 = tid, p1 = tid + 256, p2 = tid + 512;
    bool v2 = (p2 < 612);
    int p2c = v2 ? p2 : 0;
    int sr0 = p0 / 34, sc0 = p0 % 34;
    int sr1 = p1 / 34, sc1 = p1 % 34;
    int sr2 = p2c / 34, sc2 = p2c % 34;
    float a0[16], a1[16], a2[16];
#pragma unroll
    for (int oc = 0; oc < 16; ++oc) {
      float bb = b1[oc];
      a0[oc] = bb; a1[oc] = bb; a2[oc] = bb;
    }
#pragma unroll 1
    for (int ic = 0; ic < 5; ++ic) {
      const float* x0p = &xs[ic][sr0][sc0];
      const float* x1p = &xs[ic][sr1][sc1];
      const float* x2p = &xs[ic][sr2][sc2];
#pragma unroll
      for (int dy = 0; dy < 3; ++dy) {
#pragma unroll
        for (int dx = 0; dx < 3; ++dx) {
          float x0 = x0p[dy * 36 + dx];
          float x1 = x1p[dy * 36 + dx];
          float x2 = x2p[dy * 36 + dx];
          const float* wrow = w1r + (ic * 9 + dy * 3 + dx) * 16;
#pragma unroll
          for (int oc = 0; oc < 16; ++oc) {
            float w = wrow[oc];
            a0[oc] = fmaf(w, x0, a0[oc]);
            a1[oc] = fmaf(w, x1, a1[oc]);
            a2[oc] = fmaf(w, x2, a2[oc]);
          }
        }
      }
    }
    // store (zero at out-of-image positions -> implements conv2 zero pad)
    {
      int q = r0 - 1 + sr0, xp = c0 - 1 + sc0;
      bool ok = (q >= 0 && q < IMW && xp >= 0 && xp < IMW);
      float* d = &stage[(sr0 * 34 + sc0) * 20];
#pragma unroll
      for (int oc = 0; oc < 16; ++oc) d[oc] = ok ? fmaxf(a0[oc], 0.f) : 0.f;
    }
    {
      int q = r0 - 1 + sr1, xp = c0 - 1 + sc1;
      bool ok = (q >= 0 && q < IMW && xp >= 0 && xp < IMW);
      float* d = &stage[(sr1 * 34 + sc1) * 20];
#pragma unroll
      for (int oc = 0; oc < 16; ++oc) d[oc] = ok ? fmaxf(a1[oc], 0.f) : 0.f;
    }
    if (v2) {
      int q = r0 - 1 + sr2, xp = c0 - 1 + sc2;
      bool ok = (q >= 0 && q < IMW && xp >= 0 && xp < IMW);
      float* d = &stage[(sr2 * 34 + sc2) * 20];
#pragma unroll
      for (int oc = 0; oc < 16; ++oc) d[oc] = ok ? fmaxf(a2[oc], 0.f) : 0.f;
    }
  }
  __syncthreads();
  // ---- phase 2: conv2 + b2, relu. 8 oc x 8 px register tile per thread.
  int og = __builtin_amdgcn_readfirstlane(tid >> 6);  // wave-uniform
  int pg = tid & 63;
  int oc0 = og * 8;
  int prow = pg >> 2;          // 0..15
  int pcol = (pg & 3) * 8;     // 0,8,16,24
  float acc[8][8];
#pragma unroll
  for (int oc = 0; oc < 8; ++oc) {
    float bb = b2[oc0 + oc];
#pragma unroll
    for (int p = 0; p < 8; ++p) acc[oc][p] = bb;
  }
#pragma unroll 1
  for (int j = 0; j < 9; ++j) {
    int dy = j / 3, dx = j - dy * 3;
    const float* stb = &stage[((prow + dy) * 34 + pcol + dx) * 20];
#pragma unroll
    for (int icg = 0; icg < 4; ++icg) {
      float4 s4[8];
#pragma unroll
      for (int p = 0; p < 8; ++p)
        s4[p] = *(const float4*)(stb + p * 20 + icg * 4);
      const float* wp = w2r + (j * 4 + icg) * 128 + oc0 * 4;
#pragma unroll
      for (int oc = 0; oc < 8; ++oc) {
        float4 wv = *(const float4*)(wp + oc * 4);
#pragma unroll
        for (int p = 0; p < 8; ++p) {
          acc[oc][p] = fmaf(wv.x, s4[p].x, acc[oc][p]);
          acc[oc][p] = fmaf(wv.y, s4[p].y, acc[oc][p]);
          acc[oc][p] = fmaf(wv.z, s4[p].z, acc[oc][p]);
          acc[oc][p] = fmaf(wv.w, s4[p].w, acc[oc][p]);
        }
      }
    }
  }
#pragma unroll
  for (int oc = 0; oc < 8; ++oc) {
#pragma unroll
    for (int p = 0; p < 8; ++p) {
      out[(size_t)(oc0 + oc) * HW + (r0 + prow) * IMW + c0 + pcol + p] =
          fmaxf(acc[oc][p], 0.0f);
    }
  }
}

// ---------------------------------------------------------------------------
extern "C" void kernel_launch(void* const* d_in, const int* in_sizes, int n_in,
                              void* d_out, int out_size, void* d_ws,
                              size_t ws_size, hipStream_t stream) {
  const float* on_ev  = (const float*)d_in[0];
  const float* off_ev = (const float*)d_in[1];
  const float* rgb    = (const float*)d_in[2];
  const float* on_w1  = (const float*)d_in[3];
  const float* on_w2  = (const float*)d_in[4];
  const float* off_w1 = (const float*)d_in[5];
  const float* off_w2 = (const float*)d_in[6];
  const float* cw1    = (const float*)d_in[7];
  const float* cb1    = (const float*)d_in[8];
  const float* cw2    = (const float*)d_in[9];
  const float* cb2    = (const float*)d_in[10];
  float* out = (float*)d_out;
  char* ws = (char*)d_ws;
  ull* R = (ull*)ws;                          // 4 MB: spike row bitmaps
  float* means = (float*)(ws + (4u << 20));   // 2 MB: On/Off mean maps
  float* w2r = (float*)(ws + (6u << 20));     // 18 KB
  float* w1r = w2r + 4608;                    // 2.8 KB

  hipLaunchKernelGGL(k0_rearrange, dim3(18), dim3(256), 0, stream,
                     cw2, cw1, w2r, w1r);
  hipLaunchKernelGGL(k1_lif, dim3(2, 512, 2), dim3(256), 0, stream,
                     on_ev, off_ev, R);
  hipLaunchKernelGGL(k2_enc, dim3(8, 128, 2), dim3(256), 0, stream,
                     R, on_w1, on_w2, off_w1, off_w2, means);
  hipLaunchKernelGGL(k3_clip, dim3(16, 32), dim3(256), 0, stream,
                     means, rgb, w1r, cb1, w2r, cb2, out);
}

// Round 3
// 105.253 us; speedup vs baseline: 1.2284x; 1.2284x over previous
//
#include <hip/hip_runtime.h>
#include <stdint.h>

#define IMW 512
#define HW 262144  // 512*512

typedef unsigned long long ull;

// ---------------------------------------------------------------------------
// k0: rearrange clip conv weights for scalar-friendly access.
// w2r[(j*4 + ic/4)*128 + oc*4 + ic%4] = clip_w2[oc][ic][j]   (j = dy*3+dx)
// w1r[tap*16 + oc] = clip_w1[oc][tap]                        (tap = ic*9+j)
// ---------------------------------------------------------------------------
__global__ __launch_bounds__(256) void k0_rearrange(
    const float* __restrict__ cw2, const float* __restrict__ cw1,
    float* __restrict__ w2r, float* __restrict__ w1r) {
  int i = blockIdx.x * 256 + threadIdx.x;
  if (i < 4608) {
    int oc = i / 144, rem = i % 144;
    int ic = rem / 9, j = rem % 9;
    w2r[(j * 4 + (ic >> 2)) * 128 + oc * 4 + (ic & 3)] = cw2[i];
  }
  if (i < 720) {
    int oc = i / 45, tap = i % 45;
    w1r[tap * 16 + oc] = cw1[i];
  }
}

// ---------------------------------------------------------------------------
// k1: LIF scan over 64 frames. v = fmaf(x - v, 0.1f, v)  (== v + (x-v)/10
// up to ~1e-6 rounding; spike decision v>=1 has >=1.2e-3 margin for inputs
// in [0,1), so spikes match the reference's divide form exactly).
// Each wave handles 128 columns of one row: 2 LIF chains per thread for ILP.
// Spikes transposed via __ballot + predicated keep (t is a constant in the
// unrolled loop -> v_cmp + cndmask) into row bitmaps:
// R[enc][t][y][wc] = 64-bit word, bit i = spike at column wc*64+i.
// ---------------------------------------------------------------------------
__global__ __launch_bounds__(256) void k1_lif(
    const float* __restrict__ on, const float* __restrict__ off,
    ull* __restrict__ R) {
  int enc = blockIdx.z;
  const float* ev = enc ? off : on;
  int wv = threadIdx.x >> 6;     // wave 0..3 -> 128-col segment
  int lane = threadIdx.x & 63;
  int row = blockIdx.y;
  const float* p = ev + (size_t)row * IMW + wv * 128 + lane;
  float v0 = 0.f, v1 = 0.f;
  ull keep0 = 0, keep1 = 0;
#pragma unroll
  for (int t = 0; t < 64; ++t) {
    const float* q = p + (size_t)t * HW;
    float x0 = q[0];
    float x1 = q[64];
    v0 = fmaf(x0 - v0, 0.1f, v0);
    v1 = fmaf(x1 - v1, 0.1f, v1);
    bool s0 = (v0 >= 1.0f);
    bool s1 = (v1 >= 1.0f);
    ull b0 = __ballot(s0);
    ull b1 = __ballot(s1);
    if (s0) v0 = 0.f;
    if (s1) v1 = 0.f;
    // lane t keeps the ballots from step t
    keep0 = (lane == t) ? b0 : keep0;
    keep1 = (lane == t) ? b1 : keep1;
  }
  // thread (lane=l) holds words for t=l, word cols wv*2 and wv*2+1
  ull* dst = R + (((size_t)enc * 64 + lane) * IMW + row) * 8 + wv * 2;
  dst[0] = keep0;
  dst[1] = keep1;
}

// ---------------------------------------------------------------------------
// k2: encoder convs. Tile 64x4 output pixels, 1 px/thread (4 waves = 4 rows).
// Fast path: if no spike anywhere in the tile's 5x5 halo across all 64 t,
// output is exactly 0 (relu(conv2(relu(conv1(0)))) with no biases).
// Slow path: relu(conv1) via 512-entry float4 table indexed by 3x3 spike
// pattern, conv2 in registers, conv2 zero-padding handled by fm[] masks.
// ---------------------------------------------------------------------------
__global__ __launch_bounds__(256) void k2_enc(
    const ull* __restrict__ R, const float* __restrict__ on_w1,
    const float* __restrict__ on_w2, const float* __restrict__ off_w1,
    const float* __restrict__ off_w2, float* __restrict__ means) {
  __shared__ ull spk[64][8][2];   // [t][local row r0-2..r0+5][A,B]
  __shared__ float4 t1v[512];     // relu(conv1) per 9-bit pattern
  int tid = threadIdx.x;
  int enc = blockIdx.z;
  int wcb = blockIdx.x;           // 64-column word index 0..7
  int r0 = blockIdx.y * 4;
  ull any = 0;
#pragma unroll
  for (int i = 0; i < 2; ++i) {
    int pair = tid * 2 + i;       // 512 pairs = 64 t x 8 rows
    int t = pair >> 3, row = pair & 7;
    int gy = r0 - 2 + row;
    ull Wp = 0, Wc = 0, Wn = 0;
    if (gy >= 0 && gy < IMW) {
      const ull* base = R + (((size_t)enc * 64 + t) * IMW + gy) * 8;
      Wc = base[wcb];
      if (wcb > 0) Wp = base[wcb - 1];
      if (wcb < 7) Wn = base[wcb + 1];
    }
    spk[t][row][0] = (Wc << 2) | (Wp >> 62);  // A: cols C-2..C+61
    spk[t][row][1] = (Wc >> 2) | (Wn << 62);  // B: cols C+2..C+65
    any |= Wp | Wc | Wn;
  }
  int lane = tid & 63, wv = tid >> 6;
  int c = wcb * 64 + lane;
  int r = r0 + wv;
  float* outp = means + (size_t)enc * HW + r * IMW + c;
  int nz = __syncthreads_or(any != 0ull);
  if (!nz) { *outp = 0.0f; return; }

  // ---- slow path (not executed for all-zero spikes, but fully correct) ----
  const float* w1 = enc ? off_w1 : on_w1;
  const float* w2 = enc ? off_w2 : on_w2;
#pragma unroll
  for (int i = 0; i < 2; ++i) {
    int e = tid + 256 * i;
    float a0 = 0.f, a1 = 0.f, a2 = 0.f, a3 = 0.f;
#pragma unroll
    for (int k = 0; k < 9; ++k) {
      if (e & (1 << k)) {
        a0 += w1[k]; a1 += w1[9 + k]; a2 += w1[18 + k]; a3 += w1[27 + k];
      }
    }
    t1v[e] = make_float4(fmaxf(a0, 0.f), fmaxf(a1, 0.f),
                         fmaxf(a2, 0.f), fmaxf(a3, 0.f));
  }
  __syncthreads();
  float w2g[36];
#pragma unroll
  for (int i = 0; i < 36; ++i) w2g[i] = w2[i];
  float fm[9];   // conv2 zero-padding: out-of-image positions contribute 0
#pragma unroll
  for (int qi = 0; qi < 3; ++qi)
#pragma unroll
    for (int dx = 0; dx < 3; ++dx) {
      int q = r - 1 + qi, xp = c - 1 + dx;
      fm[qi * 3 + dx] =
          (q >= 0 && q < IMW && xp >= 0 && xp < IMW) ? 1.0f : 0.0f;
    }
  int selB = (lane >= 60) ? 1 : 0;
  int shamt = selB ? lane - 4 : lane;
  float acc = 0.0f;
  for (int t = 0; t < 64; ++t) {
    unsigned r5[5];
#pragma unroll
    for (int k = 0; k < 5; ++k)
      r5[k] = (unsigned)((spk[t][wv + k][selB] >> shamt) & 31ull);
    float sum = 0.0f;
#pragma unroll
    for (int qi = 0; qi < 3; ++qi) {
#pragma unroll
      for (int dx = 0; dx < 3; ++dx) {
        unsigned pat = ((r5[qi] >> dx) & 7u) |
                       (((r5[qi + 1] >> dx) & 7u) << 3) |
                       (((r5[qi + 2] >> dx) & 7u) << 6);
        float4 sv = t1v[pat];
        int j = qi * 3 + dx;
        float d = w2g[j] * sv.x + w2g[9 + j] * sv.y + w2g[18 + j] * sv.z +
                  w2g[27 + j] * sv.w;
        sum = fmaf(fm[j], d, sum);
      }
    }
    acc += fmaxf(sum, 0.0f);
  }
  *outp = acc * (1.0f / 64.0f);
}

// ---------------------------------------------------------------------------
// k3: clip convs, fused. Out tile 32x16. Phase1 builds relu(conv1+b1) for
// tile+halo (zeroed at out-of-image positions = conv2 zero padding) into LDS.
// Phase2: register tile 8 oc x 8 px per thread, weights via uniform (scalar)
// loads, stage via ds_read_b128.
// ---------------------------------------------------------------------------
__global__ __launch_bounds__(256) void k3_clip(
    const float* __restrict__ means, const float* __restrict__ rgb,
    const float* __restrict__ w1r, const float* __restrict__ b1,
    const float* __restrict__ w2r, const float* __restrict__ b2,
    float* __restrict__ out) {
  __shared__ float xs[5][20][36];       // input tile, rows r0-2.., cols c0-2..
  __shared__ float stage[18 * 34 * 20]; // [sr][sc][16 ic, padded to 20]
  int tid = threadIdx.x;
  int c0 = blockIdx.x * 32;
  int r0 = blockIdx.y * 16;
  // load x tile (On mean, Off mean, rgb x3) with zero padding
#pragma unroll
  for (int k = 0; k < 15; ++k) {
    int idx = tid + 256 * k;
    if (idx < 3600) {
      int ch = idx / 720, rem = idx % 720;
      int row = rem / 36, col = rem % 36;
      int gy = r0 - 2 + row, gx = c0 - 2 + col;
      float val = 0.0f;
      if (gy >= 0 && gy < IMW && gx >= 0 && gx < IMW) {
        val = (ch < 2) ? means[(size_t)ch * HW + gy * IMW + gx]
                       : rgb[(size_t)(ch - 2) * HW + gy * IMW + gx];
      }
      xs[ch][row][col] = val;
    }
  }
  __syncthreads();
  // ---- phase 1: stage = relu(conv1(x)+b1), 612 positions, <=3 per thread
  {
    int p0 = tid, p1 = tid + 256, p2 = tid + 512;
    bool v2 = (p2 < 612);
    int p2c = v2 ? p2 : 0;
    int sr0 = p0 / 34, sc0 = p0 % 34;
    int sr1 = p1 / 34, sc1 = p1 % 34;
    int sr2 = p2c / 34, sc2 = p2c % 34;
    float a0[16], a1[16], a2[16];
#pragma unroll
    for (int oc = 0; oc < 16; ++oc) {
      float bb = b1[oc];
      a0[oc] = bb; a1[oc] = bb; a2[oc] = bb;
    }
#pragma unroll 1
    for (int ic = 0; ic < 5; ++ic) {
      const float* x0p = &xs[ic][sr0][sc0];
      const float* x1p = &xs[ic][sr1][sc1];
      const float* x2p = &xs[ic][sr2][sc2];
#pragma unroll
      for (int dy = 0; dy < 3; ++dy) {
#pragma unroll
        for (int dx = 0; dx < 3; ++dx) {
          float x0 = x0p[dy * 36 + dx];
          float x1 = x1p[dy * 36 + dx];
          float x2 = x2p[dy * 36 + dx];
          const float* wrow = w1r + (ic * 9 + dy * 3 + dx) * 16;
#pragma unroll
          for (int oc = 0; oc < 16; ++oc) {
            float w = wrow[oc];
            a0[oc] = fmaf(w, x0, a0[oc]);
            a1[oc] = fmaf(w, x1, a1[oc]);
            a2[oc] = fmaf(w, x2, a2[oc]);
          }
        }
      }
    }
    // store (zero at out-of-image positions -> implements conv2 zero pad)
    {
      int q = r0 - 1 + sr0, xp = c0 - 1 + sc0;
      bool ok = (q >= 0 && q < IMW && xp >= 0 && xp < IMW);
      float* d = &stage[(sr0 * 34 + sc0) * 20];
#pragma unroll
      for (int oc = 0; oc < 16; ++oc) d[oc] = ok ? fmaxf(a0[oc], 0.f) : 0.f;
    }
    {
      int q = r0 - 1 + sr1, xp = c0 - 1 + sc1;
      bool ok = (q >= 0 && q < IMW && xp >= 0 && xp < IMW);
      float* d = &stage[(sr1 * 34 + sc1) * 20];
#pragma unroll
      for (int oc = 0; oc < 16; ++oc) d[oc] = ok ? fmaxf(a1[oc], 0.f) : 0.f;
    }
    if (v2) {
      int q = r0 - 1 + sr2, xp = c0 - 1 + sc2;
      bool ok = (q >= 0 && q < IMW && xp >= 0 && xp < IMW);
      float* d = &stage[(sr2 * 34 + sc2) * 20];
#pragma unroll
      for (int oc = 0; oc < 16; ++oc) d[oc] = ok ? fmaxf(a2[oc], 0.f) : 0.f;
    }
  }
  __syncthreads();
  // ---- phase 2: conv2 + b2, relu. 8 oc x 8 px register tile per thread.
  int og = __builtin_amdgcn_readfirstlane(tid >> 6);  // wave-uniform
  int pg = tid & 63;
  int oc0 = og * 8;
  int prow = pg >> 2;          // 0..15
  int pcol = (pg & 3) * 8;     // 0,8,16,24
  float acc[8][8];
#pragma unroll
  for (int oc = 0; oc < 8; ++oc) {
    float bb = b2[oc0 + oc];
#pragma unroll
    for (int p = 0; p < 8; ++p) acc[oc][p] = bb;
  }
#pragma unroll 1
  for (int j = 0; j < 9; ++j) {
    int dy = j / 3, dx = j - dy * 3;
    const float* stb = &stage[((prow + dy) * 34 + pcol + dx) * 20];
#pragma unroll
    for (int icg = 0; icg < 4; ++icg) {
      float4 s4[8];
#pragma unroll
      for (int p = 0; p < 8; ++p)
        s4[p] = *(const float4*)(stb + p * 20 + icg * 4);
      const float* wp = w2r + (j * 4 + icg) * 128 + oc0 * 4;
#pragma unroll
      for (int oc = 0; oc < 8; ++oc) {
        float4 wv = *(const float4*)(wp + oc * 4);
#pragma unroll
        for (int p = 0; p < 8; ++p) {
          acc[oc][p] = fmaf(wv.x, s4[p].x, acc[oc][p]);
          acc[oc][p] = fmaf(wv.y, s4[p].y, acc[oc][p]);
          acc[oc][p] = fmaf(wv.z, s4[p].z, acc[oc][p]);
          acc[oc][p] = fmaf(wv.w, s4[p].w, acc[oc][p]);
        }
      }
    }
  }
#pragma unroll
  for (int oc = 0; oc < 8; ++oc) {
#pragma unroll
    for (int p = 0; p < 8; ++p) {
      out[(size_t)(oc0 + oc) * HW + (r0 + prow) * IMW + c0 + pcol + p] =
          fmaxf(acc[oc][p], 0.0f);
    }
  }
}

// ---------------------------------------------------------------------------
extern "C" void kernel_launch(void* const* d_in, const int* in_sizes, int n_in,
                              void* d_out, int out_size, void* d_ws,
                              size_t ws_size, hipStream_t stream) {
  const float* on_ev  = (const float*)d_in[0];
  const float* off_ev = (const float*)d_in[1];
  const float* rgb    = (const float*)d_in[2];
  const float* on_w1  = (const float*)d_in[3];
  const float* on_w2  = (const float*)d_in[4];
  const float* off_w1 = (const float*)d_in[5];
  const float* off_w2 = (const float*)d_in[6];
  const float* cw1    = (const float*)d_in[7];
  const float* cb1    = (const float*)d_in[8];
  const float* cw2    = (const float*)d_in[9];
  const float* cb2    = (const float*)d_in[10];
  float* out = (float*)d_out;
  char* ws = (char*)d_ws;
  ull* R = (ull*)ws;                          // 4 MB: spike row bitmaps
  float* means = (float*)(ws + (4u << 20));   // 2 MB: On/Off mean maps
  float* w2r = (float*)(ws + (6u << 20));     // 18 KB
  float* w1r = w2r + 4608;                    // 2.8 KB

  hipLaunchKernelGGL(k0_rearrange, dim3(18), dim3(256), 0, stream,
                     cw2, cw1, w2r, w1r);
  hipLaunchKernelGGL(k1_lif, dim3(1, 512, 2), dim3(256), 0, stream,
                     on_ev, off_ev, R);
  hipLaunchKernelGGL(k2_enc, dim3(8, 128, 2), dim3(256), 0, stream,
                     R, on_w1, on_w2, off_w1, off_w2, means);
  hipLaunchKernelGGL(k3_clip, dim3(16, 32), dim3(256), 0, stream,
                     means, rgb, w1r, cb1, w2r, cb2, out);
}

// Round 4
// 85.657 us; speedup vs baseline: 1.5094x; 1.2288x over previous
//
#include <hip/hip_runtime.h>
#include <stdint.h>

#define IMW 512
#define HW 262144  // 512*512

typedef unsigned long long ull;

// ---------------------------------------------------------------------------
// k0: rearrange clip conv weights for scalar-friendly access.
// w2r[(j*4 + ic/4)*128 + oc*4 + ic%4] = clip_w2[oc][ic][j]   (j = dy*3+dx)
// w1r[tap*16 + oc] = clip_w1[oc][tap]                        (tap = ic*9+j)
// ---------------------------------------------------------------------------
__global__ __launch_bounds__(256) void k0_rearrange(
    const float* __restrict__ cw2, const float* __restrict__ cw1,
    float* __restrict__ w2r, float* __restrict__ w1r) {
  int i = blockIdx.x * 256 + threadIdx.x;
  if (i < 4608) {
    int oc = i / 144, rem = i % 144;
    int ic = rem / 9, j = rem % 9;
    w2r[(j * 4 + (ic >> 2)) * 128 + oc * 4 + (ic & 3)] = cw2[i];
  }
  if (i < 720) {
    int oc = i / 45, tap = i % 45;
    w1r[tap * 16 + oc] = cw1[i];
  }
}

// ---------------------------------------------------------------------------
// k1: LIF scan over 64 frames. v = fmaf(x - v, 0.1f, v)  (== v + (x-v)/10
// up to ~1e-6 rounding; spike decision v>=1 has >=1.2e-3 margin for inputs
// in [0,1), so spikes match the reference's divide form exactly).
// ---------------------------------------------------------------------------
__global__ __launch_bounds__(256) void k1_lif(
    const float* __restrict__ on, const float* __restrict__ off,
    ull* __restrict__ R) {
  int enc = blockIdx.z;
  const float* ev = enc ? off : on;
  int wv = threadIdx.x >> 6;     // wave 0..3 -> 128-col segment
  int lane = threadIdx.x & 63;
  int row = blockIdx.y;
  const float* p = ev + (size_t)row * IMW + wv * 128 + lane;
  float v0 = 0.f, v1 = 0.f;
  ull keep0 = 0, keep1 = 0;
#pragma unroll
  for (int t = 0; t < 64; ++t) {
    const float* q = p + (size_t)t * HW;
    float x0 = q[0];
    float x1 = q[64];
    v0 = fmaf(x0 - v0, 0.1f, v0);
    v1 = fmaf(x1 - v1, 0.1f, v1);
    bool s0 = (v0 >= 1.0f);
    bool s1 = (v1 >= 1.0f);
    ull b0 = __ballot(s0);
    ull b1 = __ballot(s1);
    if (s0) v0 = 0.f;
    if (s1) v1 = 0.f;
    keep0 = (lane == t) ? b0 : keep0;
    keep1 = (lane == t) ? b1 : keep1;
  }
  ull* dst = R + (((size_t)enc * 64 + lane) * IMW + row) * 8 + wv * 2;
  dst[0] = keep0;
  dst[1] = keep1;
}

// ---------------------------------------------------------------------------
// k2: encoder convs. Tile 64x4 output pixels, 1 px/thread. Fast path: if no
// spike in the tile's halo across all 64 t, output is exactly 0.
// ---------------------------------------------------------------------------
__global__ __launch_bounds__(256) void k2_enc(
    const ull* __restrict__ R, const float* __restrict__ on_w1,
    const float* __restrict__ on_w2, const float* __restrict__ off_w1,
    const float* __restrict__ off_w2, float* __restrict__ means) {
  __shared__ ull spk[64][8][2];   // [t][local row r0-2..r0+5][A,B]
  __shared__ float4 t1v[512];     // relu(conv1) per 9-bit pattern
  int tid = threadIdx.x;
  int enc = blockIdx.z;
  int wcb = blockIdx.x;           // 64-column word index 0..7
  int r0 = blockIdx.y * 4;
  ull any = 0;
#pragma unroll
  for (int i = 0; i < 2; ++i) {
    int pair = tid * 2 + i;       // 512 pairs = 64 t x 8 rows
    int t = pair >> 3, row = pair & 7;
    int gy = r0 - 2 + row;
    ull Wp = 0, Wc = 0, Wn = 0;
    if (gy >= 0 && gy < IMW) {
      const ull* base = R + (((size_t)enc * 64 + t) * IMW + gy) * 8;
      Wc = base[wcb];
      if (wcb > 0) Wp = base[wcb - 1];
      if (wcb < 7) Wn = base[wcb + 1];
    }
    spk[t][row][0] = (Wc << 2) | (Wp >> 62);  // A: cols C-2..C+61
    spk[t][row][1] = (Wc >> 2) | (Wn << 62);  // B: cols C+2..C+65
    any |= Wp | Wc | Wn;
  }
  int lane = tid & 63, wv = tid >> 6;
  int c = wcb * 64 + lane;
  int r = r0 + wv;
  float* outp = means + (size_t)enc * HW + r * IMW + c;
  int nz = __syncthreads_or(any != 0ull);
  if (!nz) { *outp = 0.0f; return; }

  // ---- slow path (not executed for all-zero spikes, but fully correct) ----
  const float* w1 = enc ? off_w1 : on_w1;
  const float* w2 = enc ? off_w2 : on_w2;
#pragma unroll
  for (int i = 0; i < 2; ++i) {
    int e = tid + 256 * i;
    float a0 = 0.f, a1 = 0.f, a2 = 0.f, a3 = 0.f;
#pragma unroll
    for (int k = 0; k < 9; ++k) {
      if (e & (1 << k)) {
        a0 += w1[k]; a1 += w1[9 + k]; a2 += w1[18 + k]; a3 += w1[27 + k];
      }
    }
    t1v[e] = make_float4(fmaxf(a0, 0.f), fmaxf(a1, 0.f),
                         fmaxf(a2, 0.f), fmaxf(a3, 0.f));
  }
  __syncthreads();
  float w2g[36];
#pragma unroll
  for (int i = 0; i < 36; ++i) w2g[i] = w2[i];
  float fm[9];   // conv2 zero-padding masks
#pragma unroll
  for (int qi = 0; qi < 3; ++qi)
#pragma unroll
    for (int dx = 0; dx < 3; ++dx) {
      int q = r - 1 + qi, xp = c - 1 + dx;
      fm[qi * 3 + dx] =
          (q >= 0 && q < IMW && xp >= 0 && xp < IMW) ? 1.0f : 0.0f;
    }
  int selB = (lane >= 60) ? 1 : 0;
  int shamt = selB ? lane - 4 : lane;
  float acc = 0.0f;
  for (int t = 0; t < 64; ++t) {
    unsigned r5[5];
#pragma unroll
    for (int k = 0; k < 5; ++k)
      r5[k] = (unsigned)((spk[t][wv + k][selB] >> shamt) & 31ull);
    float sum = 0.0f;
#pragma unroll
    for (int qi = 0; qi < 3; ++qi) {
#pragma unroll
      for (int dx = 0; dx < 3; ++dx) {
        unsigned pat = ((r5[qi] >> dx) & 7u) |
                       (((r5[qi + 1] >> dx) & 7u) << 3) |
                       (((r5[qi + 2] >> dx) & 7u) << 6);
        float4 sv = t1v[pat];
        int j = qi * 3 + dx;
        float d = w2g[j] * sv.x + w2g[9 + j] * sv.y + w2g[18 + j] * sv.z +
                  w2g[27 + j] * sv.w;
        sum = fmaf(fm[j], d, sum);
      }
    }
    acc += fmaxf(sum, 0.0f);
  }
  *outp = acc * (1.0f / 64.0f);
}

// ---------------------------------------------------------------------------
// k3: clip convs, fused. Out tile 32x16.
// Phase1: stage = relu(conv1+b1) for tile+halo (18x34 positions x 16ch),
//   zeroed at out-of-image positions (= conv2 zero padding).
// Stage layout: 16B granules, granule g = pos*4+icg stored at g^((g>>5)&7).
//   This XOR swizzle spreads the phase-2 read lanes (16 prow x 4 pcol-groups)
//   evenly over the 8 LDS bank-groups -> conflict-free ds_read_b128.
// Phase2: per thread 8 oc x 8 px. Per (dy,icg): load the 10-granule row
//   window ONCE into registers, compute all 3 dx shifts from it.
// ---------------------------------------------------------------------------
__global__ __launch_bounds__(256) void k3_clip(
    const float* __restrict__ means, const float* __restrict__ rgb,
    const float* __restrict__ w1r, const float* __restrict__ b1,
    const float* __restrict__ w2r, const float* __restrict__ b2,
    float* __restrict__ out) {
  __shared__ __align__(16) float xs[5][20][36];  // input tile + halo
  __shared__ __align__(16) float stage[2448 * 4];  // 612 pos x 4 granules
  int tid = threadIdx.x;
  int c0 = blockIdx.x * 32;
  int r0 = blockIdx.y * 16;
  // load x tile (On mean, Off mean, rgb x3) with zero padding
#pragma unroll
  for (int k = 0; k < 15; ++k) {
    int idx = tid + 256 * k;
    if (idx < 3600) {
      int ch = idx / 720, rem = idx % 720;
      int row = rem / 36, col = rem % 36;
      int gy = r0 - 2 + row, gx = c0 - 2 + col;
      float val = 0.0f;
      if (gy >= 0 && gy < IMW && gx >= 0 && gx < IMW) {
        val = (ch < 2) ? means[(size_t)ch * HW + gy * IMW + gx]
                       : rgb[(size_t)(ch - 2) * HW + gy * IMW + gx];
      }
      xs[ch][row][col] = val;
    }
  }
  __syncthreads();
  // ---- phase 1: 612 positions, <=3 per thread
  {
    int p0 = tid, p1 = tid + 256, p2 = tid + 512;
    bool v2 = (p2 < 612);
    int p2c = v2 ? p2 : 0;
    int sr0 = p0 / 34, sc0 = p0 % 34;
    int sr1 = p1 / 34, sc1 = p1 % 34;
    int sr2 = p2c / 34, sc2 = p2c % 34;
    float a0[16], a1[16], a2[16];
#pragma unroll
    for (int oc = 0; oc < 16; ++oc) {
      float bb = b1[oc];
      a0[oc] = bb; a1[oc] = bb; a2[oc] = bb;
    }
#pragma unroll 1
    for (int ic = 0; ic < 5; ++ic) {
      const float* x0p = &xs[ic][sr0][sc0];
      const float* x1p = &xs[ic][sr1][sc1];
      const float* x2p = &xs[ic][sr2][sc2];
#pragma unroll
      for (int dy = 0; dy < 3; ++dy) {
#pragma unroll
        for (int dx = 0; dx < 3; ++dx) {
          float x0 = x0p[dy * 36 + dx];
          float x1 = x1p[dy * 36 + dx];
          float x2 = x2p[dy * 36 + dx];
          const float* wrow = w1r + (ic * 9 + dy * 3 + dx) * 16;
#pragma unroll
          for (int oc = 0; oc < 16; ++oc) {
            float w = wrow[oc];
            a0[oc] = fmaf(w, x0, a0[oc]);
            a1[oc] = fmaf(w, x1, a1[oc]);
            a2[oc] = fmaf(w, x2, a2[oc]);
          }
        }
      }
    }
    // swizzled stores; zero at out-of-image positions (= conv2 zero pad)
    {
      int q = r0 - 1 + sr0, xp = c0 - 1 + sc0;
      float m = (q >= 0 && q < IMW && xp >= 0 && xp < IMW) ? 1.0f : 0.0f;
#pragma unroll
      for (int icg = 0; icg < 4; ++icg) {
        int g = (p0 << 2) | icg;
        *(float4*)&stage[(g ^ ((g >> 5) & 7)) << 2] =
            make_float4(m * fmaxf(a0[icg * 4 + 0], 0.f),
                        m * fmaxf(a0[icg * 4 + 1], 0.f),
                        m * fmaxf(a0[icg * 4 + 2], 0.f),
                        m * fmaxf(a0[icg * 4 + 3], 0.f));
      }
    }
    {
      int q = r0 - 1 + sr1, xp = c0 - 1 + sc1;
      float m = (q >= 0 && q < IMW && xp >= 0 && xp < IMW) ? 1.0f : 0.0f;
#pragma unroll
      for (int icg = 0; icg < 4; ++icg) {
        int g = (p1 << 2) | icg;
        *(float4*)&stage[(g ^ ((g >> 5) & 7)) << 2] =
            make_float4(m * fmaxf(a1[icg * 4 + 0], 0.f),
                        m * fmaxf(a1[icg * 4 + 1], 0.f),
                        m * fmaxf(a1[icg * 4 + 2], 0.f),
                        m * fmaxf(a1[icg * 4 + 3], 0.f));
      }
    }
    if (v2) {
      int q = r0 - 1 + sr2, xp = c0 - 1 + sc2;
      float m = (q >= 0 && q < IMW && xp >= 0 && xp < IMW) ? 1.0f : 0.0f;
#pragma unroll
      for (int icg = 0; icg < 4; ++icg) {
        int g = (p2 << 2) | icg;
        *(float4*)&stage[(g ^ ((g >> 5) & 7)) << 2] =
            make_float4(m * fmaxf(a2[icg * 4 + 0], 0.f),
                        m * fmaxf(a2[icg * 4 + 1], 0.f),
                        m * fmaxf(a2[icg * 4 + 2], 0.f),
                        m * fmaxf(a2[icg * 4 + 3], 0.f));
      }
    }
  }
  __syncthreads();
  // ---- phase 2: conv2 + b2, relu. 8 oc x 8 px register tile per thread.
  int og = __builtin_amdgcn_readfirstlane(tid >> 6);  // wave-uniform
  int pg = tid & 63;
  int oc0 = og * 8;
  int prow = pg >> 2;          // 0..15
  int pcol = (pg & 3) * 8;     // 0,8,16,24
  float acc[8][8];
#pragma unroll
  for (int oc = 0; oc < 8; ++oc) {
    float bb = b2[oc0 + oc];
#pragma unroll
    for (int p = 0; p < 8; ++p) acc[oc][p] = bb;
  }
#pragma unroll 1
  for (int dy = 0; dy < 3; ++dy) {
    int posbase = (prow + dy) * 34 + pcol;
#pragma unroll 1
    for (int icg = 0; icg < 4; ++icg) {
      float4 V[10];
#pragma unroll
      for (int r = 0; r < 10; ++r) {
        int g = ((posbase + r) << 2) | icg;
        V[r] = *(const float4*)&stage[(g ^ ((g >> 5) & 7)) << 2];
      }
#pragma unroll
      for (int dx = 0; dx < 3; ++dx) {
        const float* wp = w2r + ((dy * 3 + dx) * 4 + icg) * 128 + oc0 * 4;
#pragma unroll
        for (int oc = 0; oc < 8; ++oc) {
          float4 wv = *(const float4*)(wp + oc * 4);
#pragma unroll
          for (int p = 0; p < 8; ++p) {
            acc[oc][p] = fmaf(wv.x, V[p + dx].x, acc[oc][p]);
            acc[oc][p] = fmaf(wv.y, V[p + dx].y, acc[oc][p]);
            acc[oc][p] = fmaf(wv.z, V[p + dx].z, acc[oc][p]);
            acc[oc][p] = fmaf(wv.w, V[p + dx].w, acc[oc][p]);
          }
        }
      }
    }
  }
#pragma unroll
  for (int oc = 0; oc < 8; ++oc) {
#pragma unroll
    for (int p = 0; p < 8; ++p) {
      out[(size_t)(oc0 + oc) * HW + (r0 + prow) * IMW + c0 + pcol + p] =
          fmaxf(acc[oc][p], 0.0f);
    }
  }
}

// ---------------------------------------------------------------------------
extern "C" void kernel_launch(void* const* d_in, const int* in_sizes, int n_in,
                              void* d_out, int out_size, void* d_ws,
                              size_t ws_size, hipStream_t stream) {
  const float* on_ev  = (const float*)d_in[0];
  const float* off_ev = (const float*)d_in[1];
  const float* rgb    = (const float*)d_in[2];
  const float* on_w1  = (const float*)d_in[3];
  const float* on_w2  = (const float*)d_in[4];
  const float* off_w1 = (const float*)d_in[5];
  const float* off_w2 = (const float*)d_in[6];
  const float* cw1    = (const float*)d_in[7];
  const float* cb1    = (const float*)d_in[8];
  const float* cw2    = (const float*)d_in[9];
  const float* cb2    = (const float*)d_in[10];
  float* out = (float*)d_out;
  char* ws = (char*)d_ws;
  ull* R = (ull*)ws;                          // 4 MB: spike row bitmaps
  float* means = (float*)(ws + (4u << 20));   // 2 MB: On/Off mean maps
  float* w2r = (float*)(ws + (6u << 20));     // 18 KB
  float* w1r = w2r + 4608;                    // 2.8 KB

  hipLaunchKernelGGL(k0_rearrange, dim3(18), dim3(256), 0, stream,
                     cw2, cw1, w2r, w1r);
  hipLaunchKernelGGL(k1_lif, dim3(1, 512, 2), dim3(256), 0, stream,
                     on_ev, off_ev, R);
  hipLaunchKernelGGL(k2_enc, dim3(8, 128, 2), dim3(256), 0, stream,
                     R, on_w1, on_w2, off_w1, off_w2, means);
  hipLaunchKernelGGL(k3_clip, dim3(16, 32), dim3(256), 0, stream,
                     means, rgb, w1r, cb1, w2r, cb2, out);
}

// Round 5
// 83.583 us; speedup vs baseline: 1.5469x; 1.0248x over previous
//
#include <hip/hip_runtime.h>
#include <stdint.h>

#define IMW 512
#define HW 262144  // 512*512

typedef unsigned long long ull;

// ---------------------------------------------------------------------------
// k0: rearrange clip conv weights for scalar-friendly access.
// w2r[(j*4 + ic/4)*128 + oc*4 + ic%4] = clip_w2[oc][ic][j]   (j = dy*3+dx)
// w1r[tap*16 + oc] = clip_w1[oc][tap]                        (tap = ic*9+j)
// ---------------------------------------------------------------------------
__global__ __launch_bounds__(256) void k0_rearrange(
    const float* __restrict__ cw2, const float* __restrict__ cw1,
    float* __restrict__ w2r, float* __restrict__ w1r) {
  int i = blockIdx.x * 256 + threadIdx.x;
  if (i < 4608) {
    int oc = i / 144, rem = i % 144;
    int ic = rem / 9, j = rem % 9;
    w2r[(j * 4 + (ic >> 2)) * 128 + oc * 4 + (ic & 3)] = cw2[i];
  }
  if (i < 720) {
    int oc = i / 45, tap = i % 45;
    w1r[tap * 16 + oc] = cw1[i];
  }
}

// ---------------------------------------------------------------------------
// k1: LIF scan over 64 frames. v = fmaf(x - v, 0.1f, v)  (== v + (x-v)/10
// up to ~1e-6 rounding; spike margin >=1.2e-3 for inputs in [0,1)).
// ---------------------------------------------------------------------------
__global__ __launch_bounds__(256) void k1_lif(
    const float* __restrict__ on, const float* __restrict__ off,
    ull* __restrict__ R) {
  int enc = blockIdx.z;
  const float* ev = enc ? off : on;
  int wv = threadIdx.x >> 6;     // wave 0..3 -> 128-col segment
  int lane = threadIdx.x & 63;
  int row = blockIdx.y;
  const float* p = ev + (size_t)row * IMW + wv * 128 + lane;
  float v0 = 0.f, v1 = 0.f;
  ull keep0 = 0, keep1 = 0;
#pragma unroll
  for (int t = 0; t < 64; ++t) {
    const float* q = p + (size_t)t * HW;
    float x0 = q[0];
    float x1 = q[64];
    v0 = fmaf(x0 - v0, 0.1f, v0);
    v1 = fmaf(x1 - v1, 0.1f, v1);
    bool s0 = (v0 >= 1.0f);
    bool s1 = (v1 >= 1.0f);
    ull b0 = __ballot(s0);
    ull b1 = __ballot(s1);
    if (s0) v0 = 0.f;
    if (s1) v1 = 0.f;
    keep0 = (lane == t) ? b0 : keep0;
    keep1 = (lane == t) ? b1 : keep1;
  }
  ull* dst = R + (((size_t)enc * 64 + lane) * IMW + row) * 8 + wv * 2;
  dst[0] = keep0;
  dst[1] = keep1;
}

// ---------------------------------------------------------------------------
// k2: encoder convs. Tile 64x4 output pixels, 1 px/thread. Fast path: if no
// spike in the tile's halo across all 64 t, output is exactly 0.
// ---------------------------------------------------------------------------
__global__ __launch_bounds__(256) void k2_enc(
    const ull* __restrict__ R, const float* __restrict__ on_w1,
    const float* __restrict__ on_w2, const float* __restrict__ off_w1,
    const float* __restrict__ off_w2, float* __restrict__ means) {
  __shared__ ull spk[64][8][2];   // [t][local row r0-2..r0+5][A,B]
  __shared__ float4 t1v[512];     // relu(conv1) per 9-bit pattern
  int tid = threadIdx.x;
  int enc = blockIdx.z;
  int wcb = blockIdx.x;           // 64-column word index 0..7
  int r0 = blockIdx.y * 4;
  ull any = 0;
#pragma unroll
  for (int i = 0; i < 2; ++i) {
    int pair = tid * 2 + i;       // 512 pairs = 64 t x 8 rows
    int t = pair >> 3, row = pair & 7;
    int gy = r0 - 2 + row;
    ull Wp = 0, Wc = 0, Wn = 0;
    if (gy >= 0 && gy < IMW) {
      const ull* base = R + (((size_t)enc * 64 + t) * IMW + gy) * 8;
      Wc = base[wcb];
      if (wcb > 0) Wp = base[wcb - 1];
      if (wcb < 7) Wn = base[wcb + 1];
    }
    spk[t][row][0] = (Wc << 2) | (Wp >> 62);  // A: cols C-2..C+61
    spk[t][row][1] = (Wc >> 2) | (Wn << 62);  // B: cols C+2..C+65
    any |= Wp | Wc | Wn;
  }
  int lane = tid & 63, wv = tid >> 6;
  int c = wcb * 64 + lane;
  int r = r0 + wv;
  float* outp = means + (size_t)enc * HW + r * IMW + c;
  int nz = __syncthreads_or(any != 0ull);
  if (!nz) { *outp = 0.0f; return; }

  // ---- slow path (not executed for all-zero spikes, but fully correct) ----
  const float* w1 = enc ? off_w1 : on_w1;
  const float* w2 = enc ? off_w2 : on_w2;
#pragma unroll
  for (int i = 0; i < 2; ++i) {
    int e = tid + 256 * i;
    float a0 = 0.f, a1 = 0.f, a2 = 0.f, a3 = 0.f;
#pragma unroll
    for (int k = 0; k < 9; ++k) {
      if (e & (1 << k)) {
        a0 += w1[k]; a1 += w1[9 + k]; a2 += w1[18 + k]; a3 += w1[27 + k];
      }
    }
    t1v[e] = make_float4(fmaxf(a0, 0.f), fmaxf(a1, 0.f),
                         fmaxf(a2, 0.f), fmaxf(a3, 0.f));
  }
  __syncthreads();
  float w2g[36];
#pragma unroll
  for (int i = 0; i < 36; ++i) w2g[i] = w2[i];
  float fm[9];   // conv2 zero-padding masks
#pragma unroll
  for (int qi = 0; qi < 3; ++qi)
#pragma unroll
    for (int dx = 0; dx < 3; ++dx) {
      int q = r - 1 + qi, xp = c - 1 + dx;
      fm[qi * 3 + dx] =
          (q >= 0 && q < IMW && xp >= 0 && xp < IMW) ? 1.0f : 0.0f;
    }
  int selB = (lane >= 60) ? 1 : 0;
  int shamt = selB ? lane - 4 : lane;
  float acc = 0.0f;
  for (int t = 0; t < 64; ++t) {
    unsigned r5[5];
#pragma unroll
    for (int k = 0; k < 5; ++k)
      r5[k] = (unsigned)((spk[t][wv + k][selB] >> shamt) & 31ull);
    float sum = 0.0f;
#pragma unroll
    for (int qi = 0; qi < 3; ++qi) {
#pragma unroll
      for (int dx = 0; dx < 3; ++dx) {
        unsigned pat = ((r5[qi] >> dx) & 7u) |
                       (((r5[qi + 1] >> dx) & 7u) << 3) |
                       (((r5[qi + 2] >> dx) & 7u) << 6);
        float4 sv = t1v[pat];
        int j = qi * 3 + dx;
        float d = w2g[j] * sv.x + w2g[9 + j] * sv.y + w2g[18 + j] * sv.z +
                  w2g[27 + j] * sv.w;
        sum = fmaf(fm[j], d, sum);
      }
    }
    acc += fmaxf(sum, 0.0f);
  }
  *outp = acc * (1.0f / 64.0f);
}

// ---------------------------------------------------------------------------
// k3: clip convs, fused. Out tile 32x8 (1024 blocks -> 4 resident/CU, 16
// waves/CU for latency hiding; LDS ~30 KB allows 5).
// Phase1: stage = relu(conv1+b1) for tile+halo (10x34 positions x 16ch),
//   zeroed at out-of-image positions (= conv2 zero padding).
// Stage layout: 16B granules, granule g = pos*4+icg stored at g^((g>>5)&7)
//   -> both the phase-1 write and phase-2 read lane patterns spread exactly
//   8 lanes per bank-group (conflict-free b128).
// Phase2: per thread 8 oc x 4 px. Per (dy,icg): load the 6-granule row
//   window ONCE into registers, compute all 3 dx shifts from it.
// ---------------------------------------------------------------------------
__global__ __launch_bounds__(256) void k3_clip(
    const float* __restrict__ means, const float* __restrict__ rgb,
    const float* __restrict__ w1r, const float* __restrict__ b1,
    const float* __restrict__ w2r, const float* __restrict__ b2,
    float* __restrict__ out) {
  __shared__ __align__(16) float xs[5][12][36];    // input tile + halo
  __shared__ __align__(16) float stage[1360 * 4];  // 340 pos x 4 granules
  int tid = threadIdx.x;
  int c0 = blockIdx.x * 32;
  int r0 = blockIdx.y * 8;
  // load x tile (On mean, Off mean, rgb x3) with zero padding
#pragma unroll
  for (int k = 0; k < 9; ++k) {
    int idx = tid + 256 * k;
    if (idx < 2160) {
      int ch = idx / 432, rem = idx % 432;
      int row = rem / 36, col = rem % 36;
      int gy = r0 - 2 + row, gx = c0 - 2 + col;
      float val = 0.0f;
      if (gy >= 0 && gy < IMW && gx >= 0 && gx < IMW) {
        val = (ch < 2) ? means[(size_t)ch * HW + gy * IMW + gx]
                       : rgb[(size_t)(ch - 2) * HW + gy * IMW + gx];
      }
      xs[ch][row][col] = val;
    }
  }
  __syncthreads();
  // ---- phase 1: 340 positions, <=2 per thread
  {
    int p0 = tid, p1 = tid + 256;
    bool v1 = (p1 < 340);
    int p1c = v1 ? p1 : 0;
    int sr0 = p0 / 34, sc0 = p0 % 34;
    int sr1 = p1c / 34, sc1 = p1c % 34;
    float a0[16], a1[16];
#pragma unroll
    for (int oc = 0; oc < 16; ++oc) {
      float bb = b1[oc];
      a0[oc] = bb; a1[oc] = bb;
    }
#pragma unroll 1
    for (int ic = 0; ic < 5; ++ic) {
      const float* x0p = &xs[ic][sr0][sc0];
      const float* x1p = &xs[ic][sr1][sc1];
#pragma unroll
      for (int dy = 0; dy < 3; ++dy) {
#pragma unroll
        for (int dx = 0; dx < 3; ++dx) {
          float x0 = x0p[dy * 36 + dx];
          float x1 = x1p[dy * 36 + dx];
          const float* wrow = w1r + (ic * 9 + dy * 3 + dx) * 16;
#pragma unroll
          for (int oc = 0; oc < 16; ++oc) {
            float w = wrow[oc];
            a0[oc] = fmaf(w, x0, a0[oc]);
            a1[oc] = fmaf(w, x1, a1[oc]);
          }
        }
      }
    }
    // swizzled stores; zero at out-of-image positions (= conv2 zero pad)
    {
      int q = r0 - 1 + sr0, xp = c0 - 1 + sc0;
      float m = (q >= 0 && q < IMW && xp >= 0 && xp < IMW) ? 1.0f : 0.0f;
#pragma unroll
      for (int icg = 0; icg < 4; ++icg) {
        int g = (p0 << 2) | icg;
        *(float4*)&stage[(g ^ ((g >> 5) & 7)) << 2] =
            make_float4(m * fmaxf(a0[icg * 4 + 0], 0.f),
                        m * fmaxf(a0[icg * 4 + 1], 0.f),
                        m * fmaxf(a0[icg * 4 + 2], 0.f),
                        m * fmaxf(a0[icg * 4 + 3], 0.f));
      }
    }
    if (v1) {
      int q = r0 - 1 + sr1, xp = c0 - 1 + sc1;
      float m = (q >= 0 && q < IMW && xp >= 0 && xp < IMW) ? 1.0f : 0.0f;
#pragma unroll
      for (int icg = 0; icg < 4; ++icg) {
        int g = (p1 << 2) | icg;
        *(float4*)&stage[(g ^ ((g >> 5) & 7)) << 2] =
            make_float4(m * fmaxf(a1[icg * 4 + 0], 0.f),
                        m * fmaxf(a1[icg * 4 + 1], 0.f),
                        m * fmaxf(a1[icg * 4 + 2], 0.f),
                        m * fmaxf(a1[icg * 4 + 3], 0.f));
      }
    }
  }
  __syncthreads();
  // ---- phase 2: conv2 + b2, relu. 8 oc x 4 px register tile per thread.
  int og = __builtin_amdgcn_readfirstlane(tid >> 6);  // wave-uniform
  int lane = tid & 63;
  int oc0 = og * 8;
  int prow = lane >> 3;        // 0..7
  int pcol = (lane & 7) * 4;   // 0,4,..,28
  float acc[8][4];
#pragma unroll
  for (int oc = 0; oc < 8; ++oc) {
    float bb = b2[oc0 + oc];
#pragma unroll
    for (int p = 0; p < 4; ++p) acc[oc][p] = bb;
  }
#pragma unroll 1
  for (int dy = 0; dy < 3; ++dy) {
    int posbase = (prow + dy) * 34 + pcol;
#pragma unroll 1
    for (int icg = 0; icg < 4; ++icg) {
      float4 V[6];
#pragma unroll
      for (int r = 0; r < 6; ++r) {
        int g = ((posbase + r) << 2) | icg;
        V[r] = *(const float4*)&stage[(g ^ ((g >> 5) & 7)) << 2];
      }
#pragma unroll
      for (int dx = 0; dx < 3; ++dx) {
        const float* wp = w2r + ((dy * 3 + dx) * 4 + icg) * 128 + oc0 * 4;
#pragma unroll
        for (int oc = 0; oc < 8; ++oc) {
          float4 wv = *(const float4*)(wp + oc * 4);
#pragma unroll
          for (int p = 0; p < 4; ++p) {
            acc[oc][p] = fmaf(wv.x, V[p + dx].x, acc[oc][p]);
            acc[oc][p] = fmaf(wv.y, V[p + dx].y, acc[oc][p]);
            acc[oc][p] = fmaf(wv.z, V[p + dx].z, acc[oc][p]);
            acc[oc][p] = fmaf(wv.w, V[p + dx].w, acc[oc][p]);
          }
        }
      }
    }
  }
#pragma unroll
  for (int oc = 0; oc < 8; ++oc) {
#pragma unroll
    for (int p = 0; p < 4; ++p) {
      out[(size_t)(oc0 + oc) * HW + (r0 + prow) * IMW + c0 + pcol + p] =
          fmaxf(acc[oc][p], 0.0f);
    }
  }
}

// ---------------------------------------------------------------------------
extern "C" void kernel_launch(void* const* d_in, const int* in_sizes, int n_in,
                              void* d_out, int out_size, void* d_ws,
                              size_t ws_size, hipStream_t stream) {
  const float* on_ev  = (const float*)d_in[0];
  const float* off_ev = (const float*)d_in[1];
  const float* rgb    = (const float*)d_in[2];
  const float* on_w1  = (const float*)d_in[3];
  const float* on_w2  = (const float*)d_in[4];
  const float* off_w1 = (const float*)d_in[5];
  const float* off_w2 = (const float*)d_in[6];
  const float* cw1    = (const float*)d_in[7];
  const float* cb1    = (const float*)d_in[8];
  const float* cw2    = (const float*)d_in[9];
  const float* cb2    = (const float*)d_in[10];
  float* out = (float*)d_out;
  char* ws = (char*)d_ws;
  ull* R = (ull*)ws;                          // 4 MB: spike row bitmaps
  float* means = (float*)(ws + (4u << 20));   // 2 MB: On/Off mean maps
  float* w2r = (float*)(ws + (6u << 20));     // 18 KB
  float* w1r = w2r + 4608;                    // 2.8 KB

  hipLaunchKernelGGL(k0_rearrange, dim3(18), dim3(256), 0, stream,
                     cw2, cw1, w2r, w1r);
  hipLaunchKernelGGL(k1_lif, dim3(1, 512, 2), dim3(256), 0, stream,
                     on_ev, off_ev, R);
  hipLaunchKernelGGL(k2_enc, dim3(8, 128, 2), dim3(256), 0, stream,
                     R, on_w1, on_w2, off_w1, off_w2, means);
  hipLaunchKernelGGL(k3_clip, dim3(16, 64), dim3(256), 0, stream,
                     means, rgb, w1r, cb1, w2r, cb2, out);
}

// Round 6
// 63.176 us; speedup vs baseline: 2.0466x; 1.3230x over previous
//
#include <hip/hip_runtime.h>
#include <stdint.h>

#define IMW 512
#define HW 262144  // 512*512

typedef unsigned long long ull;
typedef __attribute__((ext_vector_type(4))) float f32x4;
typedef __attribute__((ext_vector_type(8))) _Float16 h8;

// ---------------------------------------------------------------------------
// k0: weight prep.
// w1r[tap*16 + oc] = clip_w1[oc][tap]  (f32, tap = ic*9 + dy*3+dx), for conv1.
// w2h[oc*160 + k]  = clip_w2[oc][ic][j] as f16, k = tap*16+ic (j=tap=dy*3+dx),
//                    zero for k >= 144 (K padded to 5 chunks of 32).
// ---------------------------------------------------------------------------
__global__ __launch_bounds__(256) void k0_rearrange(
    const float* __restrict__ cw2, const float* __restrict__ cw1,
    _Float16* __restrict__ w2h, float* __restrict__ w1r) {
  int i = blockIdx.x * 256 + threadIdx.x;
  if (i < 5120) {
    int oc = i / 160, k = i % 160;
    int tap = k >> 4, ic = k & 15;
    float v = (tap < 9) ? cw2[oc * 144 + ic * 9 + tap] : 0.0f;
    w2h[i] = (_Float16)v;
  }
  if (i < 720) {
    int oc = i / 45, tap = i % 45;
    w1r[tap * 16 + oc] = cw1[i];
  }
}

// ---------------------------------------------------------------------------
// k1: LIF scan over 64 frames. v = fmaf(x - v, 0.1f, v)  (== v + (x-v)/10
// up to ~1e-6 rounding; spike margin >=1.2e-3 for inputs in [0,1)).
// ---------------------------------------------------------------------------
__global__ __launch_bounds__(256) void k1_lif(
    const float* __restrict__ on, const float* __restrict__ off,
    ull* __restrict__ R) {
  int enc = blockIdx.z;
  const float* ev = enc ? off : on;
  int wv = threadIdx.x >> 6;     // wave 0..3 -> 128-col segment
  int lane = threadIdx.x & 63;
  int row = blockIdx.y;
  const float* p = ev + (size_t)row * IMW + wv * 128 + lane;
  float v0 = 0.f, v1 = 0.f;
  ull keep0 = 0, keep1 = 0;
#pragma unroll
  for (int t = 0; t < 64; ++t) {
    const float* q = p + (size_t)t * HW;
    float x0 = q[0];
    float x1 = q[64];
    v0 = fmaf(x0 - v0, 0.1f, v0);
    v1 = fmaf(x1 - v1, 0.1f, v1);
    bool s0 = (v0 >= 1.0f);
    bool s1 = (v1 >= 1.0f);
    ull b0 = __ballot(s0);
    ull b1 = __ballot(s1);
    if (s0) v0 = 0.f;
    if (s1) v1 = 0.f;
    keep0 = (lane == t) ? b0 : keep0;
    keep1 = (lane == t) ? b1 : keep1;
  }
  ull* dst = R + (((size_t)enc * 64 + lane) * IMW + row) * 8 + wv * 2;
  dst[0] = keep0;
  dst[1] = keep1;
}

// ---------------------------------------------------------------------------
// k2: encoder convs. Tile 64x4 output pixels, 1 px/thread. Fast path: if no
// spike in the tile's halo across all 64 t, output is exactly 0.
// ---------------------------------------------------------------------------
__global__ __launch_bounds__(256) void k2_enc(
    const ull* __restrict__ R, const float* __restrict__ on_w1,
    const float* __restrict__ on_w2, const float* __restrict__ off_w1,
    const float* __restrict__ off_w2, float* __restrict__ means) {
  __shared__ ull spk[64][8][2];   // [t][local row r0-2..r0+5][A,B]
  __shared__ float4 t1v[512];     // relu(conv1) per 9-bit pattern
  int tid = threadIdx.x;
  int enc = blockIdx.z;
  int wcb = blockIdx.x;           // 64-column word index 0..7
  int r0 = blockIdx.y * 4;
  ull any = 0;
#pragma unroll
  for (int i = 0; i < 2; ++i) {
    int pair = tid * 2 + i;       // 512 pairs = 64 t x 8 rows
    int t = pair >> 3, row = pair & 7;
    int gy = r0 - 2 + row;
    ull Wp = 0, Wc = 0, Wn = 0;
    if (gy >= 0 && gy < IMW) {
      const ull* base = R + (((size_t)enc * 64 + t) * IMW + gy) * 8;
      Wc = base[wcb];
      if (wcb > 0) Wp = base[wcb - 1];
      if (wcb < 7) Wn = base[wcb + 1];
    }
    spk[t][row][0] = (Wc << 2) | (Wp >> 62);  // A: cols C-2..C+61
    spk[t][row][1] = (Wc >> 2) | (Wn << 62);  // B: cols C+2..C+65
    any |= Wp | Wc | Wn;
  }
  int lane = tid & 63, wv = tid >> 6;
  int c = wcb * 64 + lane;
  int r = r0 + wv;
  float* outp = means + (size_t)enc * HW + r * IMW + c;
  int nz = __syncthreads_or(any != 0ull);
  if (!nz) { *outp = 0.0f; return; }

  // ---- slow path (not executed for all-zero spikes, but fully correct) ----
  const float* w1 = enc ? off_w1 : on_w1;
  const float* w2 = enc ? off_w2 : on_w2;
#pragma unroll
  for (int i = 0; i < 2; ++i) {
    int e = tid + 256 * i;
    float a0 = 0.f, a1 = 0.f, a2 = 0.f, a3 = 0.f;
#pragma unroll
    for (int k = 0; k < 9; ++k) {
      if (e & (1 << k)) {
        a0 += w1[k]; a1 += w1[9 + k]; a2 += w1[18 + k]; a3 += w1[27 + k];
      }
    }
    t1v[e] = make_float4(fmaxf(a0, 0.f), fmaxf(a1, 0.f),
                         fmaxf(a2, 0.f), fmaxf(a3, 0.f));
  }
  __syncthreads();
  float w2g[36];
#pragma unroll
  for (int i = 0; i < 36; ++i) w2g[i] = w2[i];
  float fm[9];   // conv2 zero-padding masks
#pragma unroll
  for (int qi = 0; qi < 3; ++qi)
#pragma unroll
    for (int dx = 0; dx < 3; ++dx) {
      int q = r - 1 + qi, xp = c - 1 + dx;
      fm[qi * 3 + dx] =
          (q >= 0 && q < IMW && xp >= 0 && xp < IMW) ? 1.0f : 0.0f;
    }
  int selB = (lane >= 60) ? 1 : 0;
  int shamt = selB ? lane - 4 : lane;
  float acc = 0.0f;
  for (int t = 0; t < 64; ++t) {
    unsigned r5[5];
#pragma unroll
    for (int k = 0; k < 5; ++k)
      r5[k] = (unsigned)((spk[t][wv + k][selB] >> shamt) & 31ull);
    float sum = 0.0f;
#pragma unroll
    for (int qi = 0; qi < 3; ++qi) {
#pragma unroll
      for (int dx = 0; dx < 3; ++dx) {
        unsigned pat = ((r5[qi] >> dx) & 7u) |
                       (((r5[qi + 1] >> dx) & 7u) << 3) |
                       (((r5[qi + 2] >> dx) & 7u) << 6);
        float4 sv = t1v[pat];
        int j = qi * 3 + dx;
        float d = w2g[j] * sv.x + w2g[9 + j] * sv.y + w2g[18 + j] * sv.z +
                  w2g[27 + j] * sv.w;
        sum = fmaf(fm[j], d, sum);
      }
    }
    acc += fmaxf(sum, 0.0f);
  }
  *outp = acc * (1.0f / 64.0f);
}

// ---------------------------------------------------------------------------
// k3: clip convs, fused. Out tile 8 rows x 64 cols per block (512 blocks).
// Phase1 (VALU fp32): stage = relu(conv1+b1) for tile+halo (10x66 positions),
//   zeroed outside the image (= conv2 zero padding), stored as f16 [pos][16ch]
//   (32B/pos).
// Phase2 (MFMA f16): conv2 as GEMM M=512 px, N=32 oc, K=144 (tap-major,
//   padded to 160 = 5 chunks of 32). A-frag (lane: m=l&15, k=8*(l>>4)+e) is
//   ONE ds_read_b128: 8 consecutive ic-halves of one tap. Granule index
//   2*pos+ichalf spreads 8 lanes/bank-group = structural minimum (no
//   conflicts). B-frags from global w2h^T, 10 per wave, loaded once.
//   D layout: oc=lane&15, px=(l>>4)*4+reg -> one float4 store per tile.
// ---------------------------------------------------------------------------
__global__ __launch_bounds__(256) void k3_clip(
    const float* __restrict__ means, const float* __restrict__ rgb,
    const float* __restrict__ w1r, const float* __restrict__ b1,
    const _Float16* __restrict__ w2h, const float* __restrict__ b2,
    float* __restrict__ out) {
  __shared__ __align__(16) float xs[5][12][68];        // input tile + halo
  __shared__ __align__(16) _Float16 stage[660 * 16];   // [pos][ic] f16
  int tid = threadIdx.x;
  int c0 = blockIdx.x * 64;
  int r0 = blockIdx.y * 8;
  // ---- load x tile (On mean, Off mean, rgb x3), zero-padded: 4080 elems
#pragma unroll
  for (int k = 0; k < 16; ++k) {
    int idx = tid + 256 * k;
    if (idx < 4080) {
      int ch = idx / 816, rem = idx % 816;
      int row = rem / 68, col = rem % 68;
      int gy = r0 - 2 + row, gx = c0 - 2 + col;
      float val = 0.0f;
      if (gy >= 0 && gy < IMW && gx >= 0 && gx < IMW) {
        val = (ch < 2) ? means[(size_t)ch * HW + gy * IMW + gx]
                       : rgb[(size_t)(ch - 2) * HW + gy * IMW + gx];
      }
      xs[ch][row][col] = val;
    }
  }
  __syncthreads();
  // ---- phase 1: conv1 at 660 stage positions (10 x 66), <=3 per thread
#pragma unroll 1
  for (int rep = 0; rep < 3; ++rep) {
    int p = tid + (rep << 8);
    if (p < 660) {
      int sr = p / 66, sc = p % 66;
      float a[16];
#pragma unroll
      for (int oc = 0; oc < 16; ++oc) a[oc] = b1[oc];
#pragma unroll 1
      for (int ic = 0; ic < 5; ++ic) {
        const float* xp = &xs[ic][sr][sc];
#pragma unroll
        for (int dy = 0; dy < 3; ++dy) {
#pragma unroll
          for (int dx = 0; dx < 3; ++dx) {
            float x = xp[dy * 68 + dx];
            const float* wrow = w1r + (ic * 9 + dy * 3 + dx) * 16;
#pragma unroll
            for (int oc = 0; oc < 16; ++oc)
              a[oc] = fmaf(wrow[oc], x, a[oc]);
          }
        }
      }
      int q = r0 - 1 + sr, gxp = c0 - 1 + sc;
      float msk =
          (q >= 0 && q < IMW && gxp >= 0 && gxp < IMW) ? 1.0f : 0.0f;
      unsigned w[8];
#pragma unroll
      for (int j = 0; j < 8; ++j) {
        unsigned lo = (unsigned)__builtin_bit_cast(
            unsigned short, (_Float16)(msk * fmaxf(a[2 * j], 0.f)));
        unsigned hi = (unsigned)__builtin_bit_cast(
            unsigned short, (_Float16)(msk * fmaxf(a[2 * j + 1], 0.f)));
        w[j] = lo | (hi << 16);
      }
      uint4* dst = (uint4*)((char*)stage + p * 32);
      dst[0] = make_uint4(w[0], w[1], w[2], w[3]);
      dst[1] = make_uint4(w[4], w[5], w[6], w[7]);
    }
  }
  __syncthreads();
  // ---- phase 2: conv2 via MFMA. Wave og owns m-tiles og*8 .. og*8+7.
  int og = __builtin_amdgcn_readfirstlane(tid >> 6);
  int lane = tid & 63;
  int xl = lane & 15;
  int quad = lane >> 4;          // 0..3
  int ichalf = quad & 1;
  int q2 = quad >> 1;            // tap parity within chunk
  // per-lane tap byte-offsets for the 5 K-chunks (tap 9 clamped to 8; B=0)
  int myoff[5];
#pragma unroll
  for (int c = 0; c < 5; ++c) {
    int tap = 2 * c + q2;
    if (tap > 8) tap = 8;
    myoff[c] = ((tap / 3) * 66 + (tap % 3)) * 32;
  }
  // B fragments: w2h[oc][k], lane reads 8 consecutive k at 32c + quad*8
  h8 bf[5][2];
  const char* wb = (const char*)w2h;
#pragma unroll
  for (int c = 0; c < 5; ++c) {
#pragma unroll
    for (int nt = 0; nt < 2; ++nt) {
      int oc = nt * 16 + xl;
      f32x4 t = *(const f32x4*)(wb + oc * 320 + c * 64 + quad * 16);
      bf[c][nt] = __builtin_bit_cast(h8, t);
    }
  }
  float bias0 = b2[xl];
  float bias1 = b2[16 + xl];
#pragma unroll 1
  for (int mi = 0; mi < 8; ++mi) {
    int m = og * 8 + mi;
    int py = m >> 2;
    int x0 = (m & 3) << 4;
    int bb = ((py * 66 + x0 + xl) << 5) + (ichalf << 4);
    f32x4 acc0 = {0.f, 0.f, 0.f, 0.f};
    f32x4 acc1 = {0.f, 0.f, 0.f, 0.f};
#pragma unroll
    for (int c = 0; c < 5; ++c) {
      f32x4 ar = *(const f32x4*)((const char*)stage + bb + myoff[c]);
      h8 af = __builtin_bit_cast(h8, ar);
      acc0 = __builtin_amdgcn_mfma_f32_16x16x32_f16(af, bf[c][0], acc0, 0, 0, 0);
      acc1 = __builtin_amdgcn_mfma_f32_16x16x32_f16(af, bf[c][1], acc1, 0, 0, 0);
    }
    int px = c0 + x0 + ((lane >> 4) << 2);
    float* o0 = out + (size_t)xl * HW + (r0 + py) * IMW + px;
    float* o1 = o0 + (size_t)16 * HW;
    *(float4*)o0 = make_float4(fmaxf(acc0[0] + bias0, 0.f),
                               fmaxf(acc0[1] + bias0, 0.f),
                               fmaxf(acc0[2] + bias0, 0.f),
                               fmaxf(acc0[3] + bias0, 0.f));
    *(float4*)o1 = make_float4(fmaxf(acc1[0] + bias1, 0.f),
                               fmaxf(acc1[1] + bias1, 0.f),
                               fmaxf(acc1[2] + bias1, 0.f),
                               fmaxf(acc1[3] + bias1, 0.f));
  }
}

// ---------------------------------------------------------------------------
extern "C" void kernel_launch(void* const* d_in, const int* in_sizes, int n_in,
                              void* d_out, int out_size, void* d_ws,
                              size_t ws_size, hipStream_t stream) {
  const float* on_ev  = (const float*)d_in[0];
  const float* off_ev = (const float*)d_in[1];
  const float* rgb    = (const float*)d_in[2];
  const float* on_w1  = (const float*)d_in[3];
  const float* on_w2  = (const float*)d_in[4];
  const float* off_w1 = (const float*)d_in[5];
  const float* off_w2 = (const float*)d_in[6];
  const float* cw1    = (const float*)d_in[7];
  const float* cb1    = (const float*)d_in[8];
  const float* cw2    = (const float*)d_in[9];
  const float* cb2    = (const float*)d_in[10];
  float* out = (float*)d_out;
  char* ws = (char*)d_ws;
  ull* R = (ull*)ws;                          // 4 MB: spike row bitmaps
  float* means = (float*)(ws + (4u << 20));   // 2 MB: On/Off mean maps
  float* w1r = (float*)(ws + (6u << 20));     // 2.8 KB (f32 conv1 weights)
  _Float16* w2h = (_Float16*)(ws + (6u << 20) + (16u << 10));  // 10 KB f16

  hipLaunchKernelGGL(k0_rearrange, dim3(20), dim3(256), 0, stream,
                     cw2, cw1, w2h, w1r);
  hipLaunchKernelGGL(k1_lif, dim3(1, 512, 2), dim3(256), 0, stream,
                     on_ev, off_ev, R);
  hipLaunchKernelGGL(k2_enc, dim3(8, 128, 2), dim3(256), 0, stream,
                     R, on_w1, on_w2, off_w1, off_w2, means);
  hipLaunchKernelGGL(k3_clip, dim3(8, 64), dim3(256), 0, stream,
                     means, rgb, w1r, cb1, w2h, cb2, out);
}

// Round 7
// 56.722 us; speedup vs baseline: 2.2794x; 1.1138x over previous
//
#include <hip/hip_runtime.h>
#include <stdint.h>

#define IMW 512
#define HW 262144  // 512*512

typedef unsigned long long ull;
typedef __attribute__((ext_vector_type(4))) float f32x4;
typedef __attribute__((ext_vector_type(8))) _Float16 h8;

// ---------------------------------------------------------------------------
// k0: weight prep.
// w1r[tap*16 + oc] = clip_w1[oc][tap]  (f32, tap = ic*9 + dy*3+dx), for conv1.
// w2h[oc*160 + k]  = clip_w2[oc][ic][j] as f16, k = tap*16+ic (j=tap=dy*3+dx),
//                    zero for k >= 144 (K padded to 5 chunks of 32).
// ---------------------------------------------------------------------------
__global__ __launch_bounds__(256) void k0_rearrange(
    const float* __restrict__ cw2, const float* __restrict__ cw1,
    _Float16* __restrict__ w2h, float* __restrict__ w1r) {
  int i = blockIdx.x * 256 + threadIdx.x;
  if (i < 5120) {
    int oc = i / 160, k = i % 160;
    int tap = k >> 4, ic = k & 15;
    float v = (tap < 9) ? cw2[oc * 144 + ic * 9 + tap] : 0.0f;
    w2h[i] = (_Float16)v;
  }
  if (i < 720) {
    int oc = i / 45, tap = i % 45;
    w1r[tap * 16 + oc] = cw1[i];
  }
}

// ---------------------------------------------------------------------------
// k1: LIF scan over 64 frames, 1 column per thread (2048 blocks = full wave-
// slot fill). v = fmaf(x - v, 0.1f, v) (== v + (x-v)/10 up to ~1e-6; spike
// margin >=1.2e-3 for inputs in [0,1)). Depth-8 double-buffered prefetch
// keeps 16 loads in flight. Output: per-column spike history
// R2[enc][y][x] = 64-bit word, bit t = spike at step t (coalesced stores).
// ---------------------------------------------------------------------------
__global__ __launch_bounds__(256) void k1_lif(
    const float* __restrict__ on, const float* __restrict__ off,
    ull* __restrict__ R2) {
  int enc = blockIdx.z;
  const float* ev = enc ? off : on;
  int row = blockIdx.y;
  int x = blockIdx.x * 256 + threadIdx.x;
  const float* p = ev + (size_t)row * IMW + x;
  float v = 0.0f;
  unsigned hlo = 0, hhi = 0;
  float buf[16];
#pragma unroll
  for (int j = 0; j < 8; ++j) buf[j] = p[(size_t)j * HW];
#pragma unroll
  for (int batch = 0; batch < 8; ++batch) {
    if (batch < 7) {
#pragma unroll
      for (int j = 0; j < 8; ++j)
        buf[(((batch + 1) & 1) << 3) + j] = p[(size_t)((batch + 1) * 8 + j) * HW];
    }
#pragma unroll
    for (int j = 0; j < 8; ++j) {
      int t = batch * 8 + j;
      float xv = buf[((batch & 1) << 3) + j];
      v = fmaf(xv - v, 0.1f, v);
      bool s = (v >= 1.0f);
      if (s) v = 0.0f;
      if (t < 32) hlo |= s ? (1u << t) : 0u;
      else        hhi |= s ? (1u << (t - 32)) : 0u;
    }
  }
  R2[((size_t)enc * IMW + row) * IMW + x] = ((ull)hhi << 32) | hlo;
}

// ---------------------------------------------------------------------------
// k2: encoder convs. Tile 64x4 output pixels, 1 px/thread. Reads per-column
// histories; fast path: if no spike in the tile's 8x68 halo, output is 0.
// Slow path (correct for arbitrary inputs): ballot-transpose histories into
// per-t row bitmaps, then table-based conv1 + register conv2.
// ---------------------------------------------------------------------------
__global__ __launch_bounds__(256) void k2_enc(
    const ull* __restrict__ R2, const float* __restrict__ on_w1,
    const float* __restrict__ on_w2, const float* __restrict__ off_w1,
    const float* __restrict__ off_w2, float* __restrict__ means) {
  __shared__ ull hist[8][68];     // [local row r0-2..r0+5][col wcb*64-2..+65]
  __shared__ ull spk[64][8][2];   // [t][local row][A,B]
  __shared__ float4 t1v[512];     // relu(conv1) per 9-bit pattern
  int tid = threadIdx.x;
  int enc = blockIdx.z;
  int wcb = blockIdx.x;           // 64-column word index 0..7
  int r0 = blockIdx.y * 4;
  ull any = 0;
#pragma unroll
  for (int rep = 0; rep < 3; ++rep) {
    int idx = tid + 256 * rep;
    if (idx < 544) {
      int row = idx / 68, col = idx % 68;
      int gy = r0 - 2 + row, gx = wcb * 64 - 2 + col;
      ull h = 0;
      if (gy >= 0 && gy < IMW && gx >= 0 && gx < IMW)
        h = R2[((size_t)enc * IMW + gy) * IMW + gx];
      hist[row][col] = h;
      any |= h;
    }
  }
  int lane = tid & 63, wv = tid >> 6;
  int c = wcb * 64 + lane;
  int r = r0 + wv;
  float* outp = means + (size_t)enc * HW + r * IMW + c;
  int nz = __syncthreads_or(any != 0ull);
  if (!nz) { *outp = 0.0f; return; }

  // ---- slow path (not executed for all-zero spikes, but fully correct) ----
  // transpose hist -> spk: wave wv handles rows 2wv, 2wv+1
#pragma unroll 1
  for (int r2 = 0; r2 < 2; ++r2) {
    int row = wv * 2 + r2;
    ull hA = hist[row][lane];       // bit i of word A = col C-2+i
    ull hB = hist[row][lane + 4];   // bit i of word B = col C+2+i
    for (int t = 0; t < 64; ++t) {
      ull wA = __ballot((unsigned)((hA >> t) & 1ull));
      ull wB = __ballot((unsigned)((hB >> t) & 1ull));
      if (lane == t) { spk[t][row][0] = wA; spk[t][row][1] = wB; }
    }
  }
  const float* w1 = enc ? off_w1 : on_w1;
  const float* w2 = enc ? off_w2 : on_w2;
#pragma unroll
  for (int i = 0; i < 2; ++i) {
    int e = tid + 256 * i;
    float a0 = 0.f, a1 = 0.f, a2 = 0.f, a3 = 0.f;
#pragma unroll
    for (int k = 0; k < 9; ++k) {
      if (e & (1 << k)) {
        a0 += w1[k]; a1 += w1[9 + k]; a2 += w1[18 + k]; a3 += w1[27 + k];
      }
    }
    t1v[e] = make_float4(fmaxf(a0, 0.f), fmaxf(a1, 0.f),
                         fmaxf(a2, 0.f), fmaxf(a3, 0.f));
  }
  __syncthreads();
  float w2g[36];
#pragma unroll
  for (int i = 0; i < 36; ++i) w2g[i] = w2[i];
  float fm[9];   // conv2 zero-padding masks
#pragma unroll
  for (int qi = 0; qi < 3; ++qi)
#pragma unroll
    for (int dx = 0; dx < 3; ++dx) {
      int q = r - 1 + qi, xp = c - 1 + dx;
      fm[qi * 3 + dx] =
          (q >= 0 && q < IMW && xp >= 0 && xp < IMW) ? 1.0f : 0.0f;
    }
  int selB = (lane >= 60) ? 1 : 0;
  int shamt = selB ? lane - 4 : lane;
  float acc = 0.0f;
  for (int t = 0; t < 64; ++t) {
    unsigned r5[5];
#pragma unroll
    for (int k = 0; k < 5; ++k)
      r5[k] = (unsigned)((spk[t][wv + k][selB] >> shamt) & 31ull);
    float sum = 0.0f;
#pragma unroll
    for (int qi = 0; qi < 3; ++qi) {
#pragma unroll
      for (int dx = 0; dx < 3; ++dx) {
        unsigned pat = ((r5[qi] >> dx) & 7u) |
                       (((r5[qi + 1] >> dx) & 7u) << 3) |
                       (((r5[qi + 2] >> dx) & 7u) << 6);
        float4 sv = t1v[pat];
        int j = qi * 3 + dx;
        float d = w2g[j] * sv.x + w2g[9 + j] * sv.y + w2g[18 + j] * sv.z +
                  w2g[27 + j] * sv.w;
        sum = fmaf(fm[j], d, sum);
      }
    }
    acc += fmaxf(sum, 0.0f);
  }
  *outp = acc * (1.0f / 64.0f);
}

// ---------------------------------------------------------------------------
// k3: clip convs, fused. Out tile 8 rows x 64 cols per block (512 blocks).
// Phase1 (VALU fp32): stage = relu(conv1+b1) for tile+halo (10x66 positions),
//   zeroed outside the image (= conv2 zero padding), stored as f16 [pos][16ch].
// Phase2 (MFMA f16): conv2 as GEMM M=512 px, N=32 oc, K=144 (tap-major,
//   padded to 160). A-frag = ONE ds_read_b128 (8 lanes/bank-group, no
//   conflicts). B-frags held in VGPRs. D: oc=lane&15, px=(l>>4)*4+reg.
// ---------------------------------------------------------------------------
__global__ __launch_bounds__(256) void k3_clip(
    const float* __restrict__ means, const float* __restrict__ rgb,
    const float* __restrict__ w1r, const float* __restrict__ b1,
    const _Float16* __restrict__ w2h, const float* __restrict__ b2,
    float* __restrict__ out) {
  __shared__ __align__(16) float xs[5][12][68];        // input tile + halo
  __shared__ __align__(16) _Float16 stage[660 * 16];   // [pos][ic] f16
  int tid = threadIdx.x;
  int c0 = blockIdx.x * 64;
  int r0 = blockIdx.y * 8;
  // ---- load x tile (On mean, Off mean, rgb x3), zero-padded: 4080 elems
#pragma unroll
  for (int k = 0; k < 16; ++k) {
    int idx = tid + 256 * k;
    if (idx < 4080) {
      int ch = idx / 816, rem = idx % 816;
      int row = rem / 68, col = rem % 68;
      int gy = r0 - 2 + row, gx = c0 - 2 + col;
      float val = 0.0f;
      if (gy >= 0 && gy < IMW && gx >= 0 && gx < IMW) {
        val = (ch < 2) ? means[(size_t)ch * HW + gy * IMW + gx]
                       : rgb[(size_t)(ch - 2) * HW + gy * IMW + gx];
      }
      xs[ch][row][col] = val;
    }
  }
  __syncthreads();
  // ---- phase 1: conv1 at 660 stage positions (10 x 66), <=3 per thread
#pragma unroll 1
  for (int rep = 0; rep < 3; ++rep) {
    int p = tid + (rep << 8);
    if (p < 660) {
      int sr = p / 66, sc = p % 66;
      float a[16];
#pragma unroll
      for (int oc = 0; oc < 16; ++oc) a[oc] = b1[oc];
#pragma unroll 1
      for (int ic = 0; ic < 5; ++ic) {
        const float* xp = &xs[ic][sr][sc];
#pragma unroll
        for (int dy = 0; dy < 3; ++dy) {
#pragma unroll
          for (int dx = 0; dx < 3; ++dx) {
            float x = xp[dy * 68 + dx];
            const float* wrow = w1r + (ic * 9 + dy * 3 + dx) * 16;
#pragma unroll
            for (int oc = 0; oc < 16; ++oc)
              a[oc] = fmaf(wrow[oc], x, a[oc]);
          }
        }
      }
      int q = r0 - 1 + sr, gxp = c0 - 1 + sc;
      float msk =
          (q >= 0 && q < IMW && gxp >= 0 && gxp < IMW) ? 1.0f : 0.0f;
      unsigned w[8];
#pragma unroll
      for (int j = 0; j < 8; ++j) {
        unsigned lo = (unsigned)__builtin_bit_cast(
            unsigned short, (_Float16)(msk * fmaxf(a[2 * j], 0.f)));
        unsigned hi = (unsigned)__builtin_bit_cast(
            unsigned short, (_Float16)(msk * fmaxf(a[2 * j + 1], 0.f)));
        w[j] = lo | (hi << 16);
      }
      uint4* dst = (uint4*)((char*)stage + p * 32);
      dst[0] = make_uint4(w[0], w[1], w[2], w[3]);
      dst[1] = make_uint4(w[4], w[5], w[6], w[7]);
    }
  }
  __syncthreads();
  // ---- phase 2: conv2 via MFMA. Wave og owns m-tiles og*8 .. og*8+7.
  int og = __builtin_amdgcn_readfirstlane(tid >> 6);
  int lane = tid & 63;
  int xl = lane & 15;
  int quad = lane >> 4;          // 0..3
  int ichalf = quad & 1;
  int q2 = quad >> 1;            // tap parity within chunk
  int myoff[5];
#pragma unroll
  for (int c = 0; c < 5; ++c) {
    int tap = 2 * c + q2;
    if (tap > 8) tap = 8;
    myoff[c] = ((tap / 3) * 66 + (tap % 3)) * 32;
  }
  h8 bf[5][2];
  const char* wb = (const char*)w2h;
#pragma unroll
  for (int c = 0; c < 5; ++c) {
#pragma unroll
    for (int nt = 0; nt < 2; ++nt) {
      int oc = nt * 16 + xl;
      f32x4 t = *(const f32x4*)(wb + oc * 320 + c * 64 + quad * 16);
      bf[c][nt] = __builtin_bit_cast(h8, t);
    }
  }
  float bias0 = b2[xl];
  float bias1 = b2[16 + xl];
#pragma unroll 1
  for (int mi = 0; mi < 8; ++mi) {
    int m = og * 8 + mi;
    int py = m >> 2;
    int x0 = (m & 3) << 4;
    int bb = ((py * 66 + x0 + xl) << 5) + (ichalf << 4);
    f32x4 acc0 = {0.f, 0.f, 0.f, 0.f};
    f32x4 acc1 = {0.f, 0.f, 0.f, 0.f};
#pragma unroll
    for (int c = 0; c < 5; ++c) {
      f32x4 ar = *(const f32x4*)((const char*)stage + bb + myoff[c]);
      h8 af = __builtin_bit_cast(h8, ar);
      acc0 = __builtin_amdgcn_mfma_f32_16x16x32_f16(af, bf[c][0], acc0, 0, 0, 0);
      acc1 = __builtin_amdgcn_mfma_f32_16x16x32_f16(af, bf[c][1], acc1, 0, 0, 0);
    }
    int px = c0 + x0 + ((lane >> 4) << 2);
    float* o0 = out + (size_t)xl * HW + (r0 + py) * IMW + px;
    float* o1 = o0 + (size_t)16 * HW;
    *(float4*)o0 = make_float4(fmaxf(acc0[0] + bias0, 0.f),
                               fmaxf(acc0[1] + bias0, 0.f),
                               fmaxf(acc0[2] + bias0, 0.f),
                               fmaxf(acc0[3] + bias0, 0.f));
    *(float4*)o1 = make_float4(fmaxf(acc1[0] + bias1, 0.f),
                               fmaxf(acc1[1] + bias1, 0.f),
                               fmaxf(acc1[2] + bias1, 0.f),
                               fmaxf(acc1[3] + bias1, 0.f));
  }
}

// ---------------------------------------------------------------------------
extern "C" void kernel_launch(void* const* d_in, const int* in_sizes, int n_in,
                              void* d_out, int out_size, void* d_ws,
                              size_t ws_size, hipStream_t stream) {
  const float* on_ev  = (const float*)d_in[0];
  const float* off_ev = (const float*)d_in[1];
  const float* rgb    = (const float*)d_in[2];
  const float* on_w1  = (const float*)d_in[3];
  const float* on_w2  = (const float*)d_in[4];
  const float* off_w1 = (const float*)d_in[5];
  const float* off_w2 = (const float*)d_in[6];
  const float* cw1    = (const float*)d_in[7];
  const float* cb1    = (const float*)d_in[8];
  const float* cw2    = (const float*)d_in[9];
  const float* cb2    = (const float*)d_in[10];
  float* out = (float*)d_out;
  char* ws = (char*)d_ws;
  ull* R2 = (ull*)ws;                         // 4 MB: per-column histories
  float* means = (float*)(ws + (4u << 20));   // 2 MB: On/Off mean maps
  float* w1r = (float*)(ws + (6u << 20));     // 2.8 KB (f32 conv1 weights)
  _Float16* w2h = (_Float16*)(ws + (6u << 20) + (16u << 10));  // 10 KB f16

  hipLaunchKernelGGL(k0_rearrange, dim3(20), dim3(256), 0, stream,
                     cw2, cw1, w2h, w1r);
  hipLaunchKernelGGL(k1_lif, dim3(2, 512, 2), dim3(256), 0, stream,
                     on_ev, off_ev, R2);
  hipLaunchKernelGGL(k2_enc, dim3(8, 128, 2), dim3(256), 0, stream,
                     R2, on_w1, on_w2, off_w1, off_w2, means);
  hipLaunchKernelGGL(k3_clip, dim3(8, 64), dim3(256), 0, stream,
                     means, rgb, w1r, cb1, w2h, cb2, out);
}